// Round 1
// baseline (154.529 us; speedup 1.0000x reference)
//
#include <hip/hip_runtime.h>

// Problem constants (from setup_inputs): n_class=32, n_support=16, n_query=16,
// D=1024; query rows Q = n_query*n_class = 512. Output (512, 32, 1024) fp32.
constexpr int NC = 32, NS = 16, NQ = 512, D = 1024;
constexpr int QPB = 8;   // queries per block = 4 waves x 2 queries/wave

__global__ __launch_bounds__(256, 2)
void proto_attn_kernel(const float* __restrict__ data, float* __restrict__ out) {
    const int c    = blockIdx.x;   // class
    const int qt   = blockIdx.y;   // query tile
    const int tid  = threadIdx.x;
    const int wave = tid >> 6;
    const int lane = tid & 63;

    // support[c] : 16 x 1024 fp32 = 64 KB, stored as float4 for ds_read_b128
    __shared__ float4 sup4[NS * (D / 4)];

    // ---- stage support[c] into LDS (coalesced float4) ----
    const float4* sg = reinterpret_cast<const float4*>(data + (size_t)c * NS * D);
    #pragma unroll
    for (int i = 0; i < 16; ++i)
        sup4[tid + 256 * i] = sg[tid + 256 * i];
    __syncthreads();

    // ---- load this wave's two query rows, pre-scaled by K = 2*log2(e) ----
    // tanh(x) = 1 - 2/(e^{2x}+1) = 1 - 2/(exp2(K*x)+1)
    const float K = 2.88539008177792681472f;
    const int q0 = qt * QPB + wave * 2;
    float4 qa[4], qb[4];
    const float4* qg0 = reinterpret_cast<const float4*>(data + (size_t)(NC * NS + q0) * D);
    const float4* qg1 = reinterpret_cast<const float4*>(data + (size_t)(NC * NS + q0 + 1) * D);
    #pragma unroll
    for (int j = 0; j < 4; ++j) {
        float4 t0 = qg0[lane + 64 * j];
        float4 t1 = qg1[lane + 64 * j];
        qa[j] = make_float4(t0.x * K, t0.y * K, t0.z * K, t0.w * K);
        qb[j] = make_float4(t1.x * K, t1.y * K, t1.z * K, t1.w * K);
    }

    // ---- scores: sc[q][s] = D - 2 * sum_d 1/(exp2(sup*qscaled)+1) ----
    float sc0[NS], sc1[NS];
    #pragma unroll
    for (int s = 0; s < NS; ++s) {
        float r0 = 0.f, r1 = 0.f;
        #pragma unroll
        for (int j = 0; j < 4; ++j) {
            float4 sv = sup4[s * (D / 4) + lane + 64 * j];
            r0 += __builtin_amdgcn_rcpf(__builtin_amdgcn_exp2f(sv.x * qa[j].x) + 1.f);
            r0 += __builtin_amdgcn_rcpf(__builtin_amdgcn_exp2f(sv.y * qa[j].y) + 1.f);
            r0 += __builtin_amdgcn_rcpf(__builtin_amdgcn_exp2f(sv.z * qa[j].z) + 1.f);
            r0 += __builtin_amdgcn_rcpf(__builtin_amdgcn_exp2f(sv.w * qa[j].w) + 1.f);
            r1 += __builtin_amdgcn_rcpf(__builtin_amdgcn_exp2f(sv.x * qb[j].x) + 1.f);
            r1 += __builtin_amdgcn_rcpf(__builtin_amdgcn_exp2f(sv.y * qb[j].y) + 1.f);
            r1 += __builtin_amdgcn_rcpf(__builtin_amdgcn_exp2f(sv.z * qb[j].z) + 1.f);
            r1 += __builtin_amdgcn_rcpf(__builtin_amdgcn_exp2f(sv.w * qb[j].w) + 1.f);
        }
        // wave64 butterfly reduction
        #pragma unroll
        for (int m = 32; m >= 1; m >>= 1) {
            r0 += __shfl_xor(r0, m, 64);
            r1 += __shfl_xor(r1, m, 64);
        }
        sc0[s] = (float)D - 2.f * r0;
        sc1[s] = (float)D - 2.f * r1;
    }

    // ---- softmax over s (16 values, replicated in every lane) ----
    const float L2E = 1.44269504088896340736f;
    float m0 = sc0[0], m1 = sc1[0];
    #pragma unroll
    for (int s = 1; s < NS; ++s) { m0 = fmaxf(m0, sc0[s]); m1 = fmaxf(m1, sc1[s]); }
    float sum0 = 0.f, sum1 = 0.f;
    #pragma unroll
    for (int s = 0; s < NS; ++s) {
        sc0[s] = __builtin_amdgcn_exp2f((sc0[s] - m0) * L2E);
        sc1[s] = __builtin_amdgcn_exp2f((sc1[s] - m1) * L2E);
        sum0 += sc0[s];
        sum1 += sc1[s];
    }
    const float inv0 = __builtin_amdgcn_rcpf(sum0);
    const float inv1 = __builtin_amdgcn_rcpf(sum1);

    // ---- proto: out[q,c,:] = sum_s att[s] * support[c,s,:] ----
    float4 o0[4], o1[4];
    #pragma unroll
    for (int j = 0; j < 4; ++j) {
        o0[j] = make_float4(0.f, 0.f, 0.f, 0.f);
        o1[j] = make_float4(0.f, 0.f, 0.f, 0.f);
    }
    #pragma unroll
    for (int s = 0; s < NS; ++s) {
        const float a0 = sc0[s] * inv0;
        const float a1 = sc1[s] * inv1;
        #pragma unroll
        for (int j = 0; j < 4; ++j) {
            float4 sv = sup4[s * (D / 4) + lane + 64 * j];
            o0[j].x += a0 * sv.x; o0[j].y += a0 * sv.y;
            o0[j].z += a0 * sv.z; o0[j].w += a0 * sv.w;
            o1[j].x += a1 * sv.x; o1[j].y += a1 * sv.y;
            o1[j].z += a1 * sv.z; o1[j].w += a1 * sv.w;
        }
    }
    float4* og0 = reinterpret_cast<float4*>(out + ((size_t)q0 * NC + c) * D);
    float4* og1 = reinterpret_cast<float4*>(out + ((size_t)(q0 + 1) * NC + c) * D);
    #pragma unroll
    for (int j = 0; j < 4; ++j) {
        og0[lane + 64 * j] = o0[j];
        og1[lane + 64 * j] = o1[j];
    }
}

extern "C" void kernel_launch(void* const* d_in, const int* in_sizes, int n_in,
                              void* d_out, int out_size, void* d_ws, size_t ws_size,
                              hipStream_t stream) {
    (void)in_sizes; (void)n_in; (void)out_size; (void)d_ws; (void)ws_size;
    const float* data = (const float*)d_in[0];
    float* out = (float*)d_out;
    dim3 grid(NC, NQ / QPB);   // 32 classes x 64 query tiles = 2048 blocks
    proto_attn_kernel<<<grid, dim3(256), 0, stream>>>(data, out);
}